// Round 1
// baseline (171.111 us; speedup 1.0000x reference)
//
#include <hip/hip_runtime.h>
#include <hip/hip_bf16.h>
#include <stdint.h>

// Problem constants
#define B_SZ   1024
#define GF     512
#define GC     63
#define NLEAF  64
#define IN_F   512
#define OUT_F  512

typedef float f32x4 __attribute__((ext_vector_type(4)));
typedef __bf16 bf16x8 __attribute__((ext_vector_type(8)));

struct alignas(16) BV8 { __hip_bfloat162 a, b, c, d; };
union PK8 { BV8 v; bf16x8 f; };
union BU { __hip_bfloat162 h; unsigned int u; };

__device__ inline void pack8(const float* f, __hip_bfloat16* dst) {
  BU a, b, c, d;
  a.h = __float22bfloat162_rn(make_float2(f[0], f[1]));
  b.h = __float22bfloat162_rn(make_float2(f[2], f[3]));
  c.h = __float22bfloat162_rn(make_float2(f[4], f[5]));
  d.h = __float22bfloat162_rn(make_float2(f[6], f[7]));
  *(uint4*)dst = make_uint4(a.u, b.u, c.u, d.u);
}

// ---------------------------------------------------------------------------
// Kernel 1: gatings = sigmoid(x_gating @ gw + gb); leaf_probs tree product.
// (unchanged — proven)
// ---------------------------------------------------------------------------
__global__ __launch_bounds__(512, 2) void k_leafprobs(
    const float* __restrict__ xg, const float* __restrict__ gw,
    const float* __restrict__ gb, float* __restrict__ p_ws)
{
  __shared__ float xsr[GF];
  __shared__ float part[512];
  __shared__ float gates[GC + 1];
  const int b = blockIdx.x;
  const int t = threadIdx.x;

  xsr[t] = xg[(size_t)b * GF + t];
  __syncthreads();

  const int ks = t >> 6, g = t & 63;
  float acc = 0.f;
  if (g < GC) {
    const float* gp = gw + (size_t)(ks * 64) * GC + g;
    const float* xp = &xsr[ks * 64];
#pragma unroll 8
    for (int k = 0; k < 64; ++k) acc += xp[k] * gp[(size_t)k * GC];
  }
  part[t] = acc;
  __syncthreads();

  if (t < GC) {
    float s = gb[t];
#pragma unroll
    for (int r = 0; r < 8; ++r) s += part[r * 64 + t];
    gates[t] = 1.f / (1.f + expf(-s));
  }
  __syncthreads();

  if (t < NLEAF) {
    float v = 1.f;
    int idx = 0, start = 0;
#pragma unroll
    for (int d = 0; d < 6; ++d) {
      int bit = (t >> (5 - d)) & 1;
      float gg = gates[start + idx];
      v *= bit ? (1.f - gg) : gg;
      idx = 2 * idx + bit;
      start += (1 << d);
    }
    p_ws[(size_t)b * NLEAF + t] = v;
  }
}

// ---------------------------------------------------------------------------
// Kernel 2 (FUSED, restructured):
// out[b][o] (+)= sum_{i,l} (x[b,i]*p[b,l]) * pw[o][i][l]
// BM=256, BN=64, SK=16, KI=32 — same tiling/traffic as before, but:
//   * 512 threads (8 waves, wave owns 32 rows) -> 4 waves/SIMD resident
//   * stage-AHEAD double buffer: stage tile it+1 into bs[buf^1] while
//     computing tile it from bs[buf]; ONE barrier/iter, stage off crit path
//   * raw lgkmcnt(0)+s_barrier (no vmcnt drain) -> 3-deep global B prefetch
//     stays in flight across barriers
//   * xs transposed fp32 [KI][256] (32 KB), broadcast-friendly reads
// bid -> (nt=bid&7, mt=(bid>>3)&3, kc=bid>>5): 4 mt-blocks of a (nt,kc)
// pw-slice co-XCD -> pw HBM-read once, L2 serves mt-reuse.
// ---------------------------------------------------------------------------
#define SK 16
#define KI 32   // 512 / SK

template <bool ATOMIC>
__global__ __launch_bounds__(512, 4) void k_fused(
    const float* __restrict__ x_leaf,   // [1024][512]
    const float* __restrict__ p_ws,     // [1024][64]
    const float* __restrict__ pw,       // [512][512][64]  ([o][i][l])
    float* __restrict__ dst)            // parts [SK][1024][512] or out
{
  __shared__ __align__(16) float           xs[KI][256];     // 32 KB (transposed)
  __shared__ __align__(16) __hip_bfloat16  bs[2][64 * 72];  // +8 pad: 18.4 KB

  const int tid  = threadIdx.x;
  const int lane = tid & 63;
  const int wid  = tid >> 6;        // 0..7
  const int quad = lane >> 4;
  const int l15  = lane & 15;

  const int bid = blockIdx.x;       // 512
  const int nt  = bid & 7;
  const int mt  = (bid >> 3) & 3;
  const int kc  = bid >> 5;         // 0..15

  const int row_m0 = mt * 256;
  const int o0     = nt * 64;
  const int i0     = kc * KI;
  const int wm     = wid * 32;      // 32 rows per wave

  // ---- stage x slab transposed [KI][256]: thread = (row=tid&255, half) ----
  {
    const int r = tid & 255;
    const int h = tid >> 8;         // 0..1, 16 cols each
    const float4* src = (const float4*)(x_leaf + (size_t)(row_m0 + r) * IN_F + i0 + h * 16);
#pragma unroll
    for (int q = 0; q < 4; ++q) {
      float4 v = src[q];
      const int c = h * 16 + q * 4;
      xs[c + 0][r] = v.x; xs[c + 1][r] = v.y;
      xs[c + 2][r] = v.z; xs[c + 3][r] = v.w;
    }
  }

  // ---- p fragments fp32 (reused all K): pr[mi][ks][half4] ----
  f32x4 pr[2][2][2];
#pragma unroll
  for (int mi = 0; mi < 2; ++mi) {
    const int row = row_m0 + wm + mi * 16 + l15;
#pragma unroll
    for (int ks = 0; ks < 2; ++ks) {
      const f32x4* src = (const f32x4*)(p_ws + (size_t)row * NLEAF + ks * 32 + quad * 8);
      pr[mi][ks][0] = src[0];
      pr[mi][ks][1] = src[1];
    }
  }

  // ---- B-load geometry: thread = (br = tid>>3 of 64 o-rows, seg = tid&7) ----
  const int br  = tid >> 3;
  const int seg = tid & 7;
  const float* bsrc0 = pw + ((size_t)(o0 + br) * IN_F + i0) * NLEAF + seg * 8;

  f32x4 acc[2][4];
#pragma unroll
  for (int mi = 0; mi < 2; ++mi)
#pragma unroll
    for (int ni = 0; ni < 4; ++ni)
      acc[mi][ni] = (f32x4)(0.f);

  float4 rb[2][2];   // 2-deep register prefetch of the fp32 B tile (32 B/thread)

#define BLOAD(T, BUF)                                                         \
  {                                                                           \
    const float4* s_ = (const float4*)(bsrc0 + (size_t)(T) * NLEAF);          \
    rb[BUF][0] = s_[0]; rb[BUF][1] = s_[1];                                   \
  }

#define BSTAGE(BUF)                                                           \
  {                                                                           \
    float f_[8];                                                              \
    *(float4*)&f_[0] = rb[BUF][0];                                            \
    *(float4*)&f_[4] = rb[BUF][1];                                            \
    pack8(f_, &bs[BUF][br * 72 + seg * 8]);                                   \
  }

  // own DS ops drained, then workgroup barrier — NO vmcnt drain, so the
  // global B-prefetch stays in flight across the barrier.
#define BARRIER() asm volatile("s_waitcnt lgkmcnt(0)\n\ts_barrier" ::: "memory")

  // ---- prologue: tile0 staged, tiles 1&2 in flight ----
  BLOAD(0, 0)
  BLOAD(1, 1)
  BSTAGE(0)          // waits only on rb[0]'s loads
  BLOAD(2, 0)
  BARRIER();         // xs + bs[0] visible

#pragma unroll 2
  for (int it = 0; it < KI; ++it) {
    const int buf = it & 1;

    // stage NEXT tile (it+1) into bs[buf^1] — overlaps with compute below
    if (it + 1 < KI) {
      BSTAGE(buf ^ 1)
      if (it + 3 < KI) BLOAD(it + 3, buf ^ 1)
    }

    float xv[2];
    xv[0] = xs[it][wm + l15];
    xv[1] = xs[it][wm + 16 + l15];

    const __hip_bfloat16* bsc = &bs[buf][0];
    __builtin_amdgcn_s_setprio(1);
#pragma unroll
    for (int ks = 0; ks < 2; ++ks) {
      bf16x8 af[2];
#pragma unroll
      for (int mi = 0; mi < 2; ++mi) {
        f32x4 lo = pr[mi][ks][0] * xv[mi];
        f32x4 hi = pr[mi][ks][1] * xv[mi];
        PK8 u;
        u.v.a = __float22bfloat162_rn(make_float2(lo.x, lo.y));
        u.v.b = __float22bfloat162_rn(make_float2(lo.z, lo.w));
        u.v.c = __float22bfloat162_rn(make_float2(hi.x, hi.y));
        u.v.d = __float22bfloat162_rn(make_float2(hi.z, hi.w));
        af[mi] = u.f;
      }
#pragma unroll
      for (int ni = 0; ni < 4; ++ni) {
        bf16x8 bfr = *(const bf16x8*)&bsc[(ni * 16 + l15) * 72 + ks * 32 + quad * 8];
#pragma unroll
        for (int mi = 0; mi < 2; ++mi)
          acc[mi][ni] = __builtin_amdgcn_mfma_f32_16x16x32_bf16(
              af[mi], bfr, acc[mi][ni], 0, 0, 0);
      }
    }
    __builtin_amdgcn_s_setprio(0);

    BARRIER();       // reads of bs[buf] done; writes of bs[buf^1] visible
  }
#undef BLOAD
#undef BSTAGE
#undef BARRIER

  // ---- epilogue ----
#pragma unroll
  for (int mi = 0; mi < 2; ++mi) {
#pragma unroll
    for (int ni = 0; ni < 4; ++ni) {
      int row = row_m0 + wm + mi * 16 + quad * 4;
      int col = o0 + ni * 16 + l15;
      if (ATOMIC) {
        float* o = dst + (size_t)row * OUT_F + col;
        atomicAdd(o,             acc[mi][ni][0]);
        atomicAdd(o + OUT_F,     acc[mi][ni][1]);
        atomicAdd(o + 2 * OUT_F, acc[mi][ni][2]);
        atomicAdd(o + 3 * OUT_F, acc[mi][ni][3]);
      } else {
        float* o = dst + ((size_t)kc << 19) + (size_t)row * OUT_F + col;
        o[0]         = acc[mi][ni][0];
        o[OUT_F]     = acc[mi][ni][1];
        o[2 * OUT_F] = acc[mi][ni][2];
        o[3 * OUT_F] = acc[mi][ni][3];
      }
    }
  }
}

// ---------------------------------------------------------------------------
// Kernel 3: out[b][o] = sum_kc parts[kc][b][o] + sum_l p[b][l]*pb[o][l]
// (unchanged; nparts==0 -> bias-only init for atomic fallback)
// ---------------------------------------------------------------------------
__global__ __launch_bounds__(256, 4) void k_reduce(
    const float* __restrict__ parts, const float* __restrict__ p_ws,
    const float* __restrict__ pb, float* __restrict__ out, int nparts)
{
  __shared__ float ps_l[2 * NLEAF];
  const int t  = threadIdx.x;
  const int b0 = blockIdx.x * 2;

  if (t < 32)
    ((f32x4*)ps_l)[t] = ((const f32x4*)(p_ws + (size_t)b0 * NLEAF))[t];
  __syncthreads();

  const int row = b0 + (t >> 7);
  const int c0  = (t & 127) * 4;
  const f32x4* ps = (const f32x4*)&ps_l[(t >> 7) * NLEAF];

  f32x4 a;
#pragma unroll
  for (int jo = 0; jo < 4; ++jo) {
    const f32x4* pbo = (const f32x4*)(pb + (size_t)(c0 + jo) * NLEAF);
    f32x4 s = (f32x4)(0.f);
#pragma unroll
    for (int lv = 0; lv < 16; ++lv) s += pbo[lv] * ps[lv];
    a[jo] = s.x + s.y + s.z + s.w;
  }

#pragma unroll 8
  for (int k = 0; k < nparts; ++k)
    a += *(const f32x4*)(parts + ((size_t)k << 19) + (size_t)row * OUT_F + c0);

  *(f32x4*)(out + (size_t)row * OUT_F + c0) = a;
}

// ---------------------------------------------------------------------------
extern "C" void kernel_launch(void* const* d_in, const int* in_sizes, int n_in,
                              void* d_out, int out_size, void* d_ws, size_t ws_size,
                              hipStream_t stream) {
  const float* xg = (const float*)d_in[0];   // x_gating [1024][512]
  const float* xl = (const float*)d_in[1];   // x_leaf   [1024][512]
  const float* gw = (const float*)d_in[2];   // [512][63]
  const float* gb = (const float*)d_in[3];   // [63]
  const float* pw = (const float*)d_in[4];   // [512][512][64]
  const float* pb = (const float*)d_in[5];   // [512][64]
  float* out = (float*)d_out;

  // ws: p fp32 (256 KB) | parts fp32 [SK][1024][512] (32 MB)
  const size_t P_BYTES = (size_t)B_SZ * NLEAF * 4;
  const size_t SLICE   = (size_t)B_SZ * OUT_F * 4;

  float* p_ws  = (float*)d_ws;
  float* parts = (float*)((char*)d_ws + P_BYTES);

  k_leafprobs<<<dim3(B_SZ), dim3(512), 0, stream>>>(xg, gw, gb, p_ws);

  if (ws_size >= P_BYTES + SK * SLICE) {
    k_fused<false><<<dim3(512), dim3(512), 0, stream>>>(xl, p_ws, pw, parts);
    k_reduce<<<dim3(512), dim3(256), 0, stream>>>(parts, p_ws, pb, out, SK);
  } else {
    k_reduce<<<dim3(512), dim3(256), 0, stream>>>(parts, p_ws, pb, out, 0);
    k_fused<true><<<dim3(512), dim3(512), 0, stream>>>(xl, p_ws, pw, out);
  }
}

// Round 3
// 167.386 us; speedup vs baseline: 1.0223x; 1.0223x over previous
//
#include <hip/hip_runtime.h>
#include <stdint.h>

// Problem constants
#define B_SZ   1024
#define GF     512
#define GC     63
#define NLEAF  64
#define IN_F   512
#define OUT_F  512

typedef float f32x4 __attribute__((ext_vector_type(4)));
// builtin-facing half types (__fp16: what cvt_pkrtz / mfma_f16 use on this toolchain)
typedef __fp16 h16x2 __attribute__((ext_vector_type(2)));
typedef __fp16 h16x8 __attribute__((ext_vector_type(8)));
// arithmetic half types (_Float16: native packed math)
typedef _Float16 f16x2 __attribute__((ext_vector_type(2)));

union HF8 { f16x2 h2[4]; h16x8 v; uint4 u; };

__device__ inline f16x2 pkrtz(float a, float b) {
  union { h16x2 r; f16x2 f; } u;
  u.r = __builtin_amdgcn_cvt_pkrtz(a, b);
  return u.f;
}

// ---------------------------------------------------------------------------
// Kernel 1: gatings = sigmoid(x_gating @ gw + gb); leaf_probs tree product.
// (unchanged — proven)
// ---------------------------------------------------------------------------
__global__ __launch_bounds__(512, 2) void k_leafprobs(
    const float* __restrict__ xg, const float* __restrict__ gw,
    const float* __restrict__ gb, float* __restrict__ p_ws)
{
  __shared__ float xsr[GF];
  __shared__ float part[512];
  __shared__ float gates[GC + 1];
  const int b = blockIdx.x;
  const int t = threadIdx.x;

  xsr[t] = xg[(size_t)b * GF + t];
  __syncthreads();

  const int ks = t >> 6, g = t & 63;
  float acc = 0.f;
  if (g < GC) {
    const float* gp = gw + (size_t)(ks * 64) * GC + g;
    const float* xp = &xsr[ks * 64];
#pragma unroll 8
    for (int k = 0; k < 64; ++k) acc += xp[k] * gp[(size_t)k * GC];
  }
  part[t] = acc;
  __syncthreads();

  if (t < GC) {
    float s = gb[t];
#pragma unroll
    for (int r = 0; r < 8; ++r) s += part[r * 64 + t];
    gates[t] = 1.f / (1.f + expf(-s));
  }
  __syncthreads();

  if (t < NLEAF) {
    float v = 1.f;
    int idx = 0, start = 0;
#pragma unroll
    for (int d = 0; d < 6; ++d) {
      int bit = (t >> (5 - d)) & 1;
      float gg = gates[start + idx];
      v *= bit ? (1.f - gg) : gg;
      idx = 2 * idx + bit;
      start += (1 << d);
    }
    p_ws[(size_t)b * NLEAF + t] = v;
  }
}

// ---------------------------------------------------------------------------
// Kernel 2 (FUSED, latency-fixed):
// out[b][o] (+)= sum_{i,l} (x[b,i]*p[b,l]) * pw[o][i][l]
// BM=256, BN=64, SK=16, KI=32; 256 thr (4 waves, mi=4 reuse).
//  * 4-deep global B prefetch (rb[4]) -> stage waits on a tile issued
//    ~3 compute-phases (~900cy) earlier: covers HBM miss latency
//  * stage AFTER compute: MFMAs issue before the vmcnt wait each iter
//  * ONE lgkm-only barrier/iter (never drains vmcnt)
//  * f16 path: A = pk_mul(f16(p), f16(x)); B staged via cvt_pkrtz.
//    Same MFMA rate as bf16, A-build VALU cost /3, better mantissa.
//  * bs[2][64][64] f16 with byte ^= ((row&7)<<4) XOR swizzle:
//    both write (slot=(2*seg)^(br&7)) and read (slot=(ks*4+quad)^l7)
//    patterns are <=2-way per bank-group -> effectively conflict-free.
// ---------------------------------------------------------------------------
#define SK 16
#define KI 32   // 512 / SK

template <bool ATOMIC>
__global__ __launch_bounds__(256, 2) void k_fused(
    const float* __restrict__ x_leaf,   // [1024][512]
    const float* __restrict__ p_ws,     // [1024][64]
    const float* __restrict__ pw,       // [512][512][64]  ([o][i][l])
    float* __restrict__ dst)            // parts [SK][1024][512] or out
{
  __shared__ __align__(16) float         xs[KI][256];   // 32 KB (transposed)
  __shared__ __align__(16) unsigned char bs8[2 * 8192]; // 16 KB f16, swizzled

  const int tid  = threadIdx.x;
  const int lane = tid & 63;
  const int wid  = tid >> 6;        // 0..3
  const int quad = lane >> 4;
  const int l15  = lane & 15;
  const int l7   = l15 & 7;

  const int bid = blockIdx.x;       // 512
  const int nt  = bid & 7;
  const int mt  = (bid >> 3) & 3;
  const int kc  = bid >> 5;         // 0..15

  const int row_m0 = mt * 256;
  const int o0     = nt * 64;
  const int i0     = kc * KI;
  const int wm     = wid * 64;      // 64 rows per wave

  // ---- stage x slab transposed [KI][256]: one row per thread ----
  {
    const float* src = x_leaf + (size_t)(row_m0 + tid) * IN_F + i0;
#pragma unroll
    for (int q = 0; q < 8; ++q) {
      float4 v = *(const float4*)(src + q * 4);
      xs[q * 4 + 0][tid] = v.x;
      xs[q * 4 + 1][tid] = v.y;
      xs[q * 4 + 2][tid] = v.z;
      xs[q * 4 + 3][tid] = v.w;
    }
  }

  // ---- p fragments, converted ONCE to f16 (reused all K) ----
  HF8 prh[4][2];
#pragma unroll
  for (int mi = 0; mi < 4; ++mi) {
    const int row = row_m0 + wm + mi * 16 + l15;
#pragma unroll
    for (int ks = 0; ks < 2; ++ks) {
      const f32x4* src = (const f32x4*)(p_ws + (size_t)row * NLEAF + ks * 32 + quad * 8);
      f32x4 lo = src[0], hi = src[1];
      prh[mi][ks].h2[0] = pkrtz(lo.x, lo.y);
      prh[mi][ks].h2[1] = pkrtz(lo.z, lo.w);
      prh[mi][ks].h2[2] = pkrtz(hi.x, hi.y);
      prh[mi][ks].h2[3] = pkrtz(hi.z, hi.w);
    }
  }

  // ---- B-load geometry: thread = (br = tid>>2 of 64 o-rows, seg = tid&3) ----
  const int br  = tid >> 2;
  const int seg = tid & 3;
  const float* bsrc0 = pw + ((size_t)(o0 + br) * IN_F + i0) * NLEAF + seg * 16;

  // swizzled LDS offsets (XOR touches byte bits 4-6 only; fields don't carry)
  const int wsw   = (br & 7) << 4;
  const int woff0 = br * 128 + ((seg * 32) ^ wsw);
  const int woff1 = br * 128 + ((seg * 32 + 16) ^ wsw);
  int coff[2];
#pragma unroll
  for (int ks = 0; ks < 2; ++ks)
    coff[ks] = (ks * 64 + quad * 16) ^ (l7 << 4);
  const int rbase = l15 * 128;

  f32x4 acc[4][4];
#pragma unroll
  for (int mi = 0; mi < 4; ++mi)
#pragma unroll
    for (int ni = 0; ni < 4; ++ni)
      acc[mi][ni] = (f32x4)(0.f);

  float4 rb[4][4];   // 4-deep register prefetch of the fp32 B tile (16 fl/thr)

#define BLOAD(T, SLOT)                                                        \
  {                                                                           \
    const float4* s_ = (const float4*)(bsrc0 + (size_t)(T) * NLEAF);          \
    rb[SLOT][0] = s_[0]; rb[SLOT][1] = s_[1];                                 \
    rb[SLOT][2] = s_[2]; rb[SLOT][3] = s_[3];                                 \
  }

#define BSTAGE(SLOT, BUF)                                                     \
  {                                                                           \
    HF8 c0_, c1_;                                                             \
    float4 a0_ = rb[SLOT][0], a1_ = rb[SLOT][1];                              \
    float4 a2_ = rb[SLOT][2], a3_ = rb[SLOT][3];                              \
    c0_.h2[0] = pkrtz(a0_.x, a0_.y);                                          \
    c0_.h2[1] = pkrtz(a0_.z, a0_.w);                                          \
    c0_.h2[2] = pkrtz(a1_.x, a1_.y);                                          \
    c0_.h2[3] = pkrtz(a1_.z, a1_.w);                                          \
    c1_.h2[0] = pkrtz(a2_.x, a2_.y);                                          \
    c1_.h2[1] = pkrtz(a2_.z, a2_.w);                                          \
    c1_.h2[2] = pkrtz(a3_.x, a3_.y);                                          \
    c1_.h2[3] = pkrtz(a3_.z, a3_.w);                                          \
    *(uint4*)(bs8 + (BUF) * 8192 + woff0) = c0_.u;                            \
    *(uint4*)(bs8 + (BUF) * 8192 + woff1) = c1_.u;                            \
  }

  // own DS ops drained, then workgroup barrier — NO vmcnt drain: the global
  // B-prefetch (up to 4 tiles / 16 loads) stays in flight across barriers.
#define BARRIER() asm volatile("s_waitcnt lgkmcnt(0)\n\ts_barrier" ::: "memory")

// one pipeline step: compute bs[BUF] from tile IT, then stage tile IT+1
// (slot SNX) into bs[BUF^1], then refill slot SNX with tile IT+5.
#define STEP(IT, BUF, SNX)                                                    \
  {                                                                           \
    float xvf[4];                                                             \
    _Float16 xh[4];                                                           \
    _Pragma("unroll")                                                         \
    for (int mi = 0; mi < 4; ++mi) xvf[mi] = xs[(IT)][wm + mi * 16 + l15];    \
    _Pragma("unroll")                                                         \
    for (int mi = 0; mi < 4; ++mi) xh[mi] = (_Float16)xvf[mi];                \
    const unsigned char* bsr_ = bs8 + (BUF) * 8192;                           \
    __builtin_amdgcn_s_setprio(1);                                            \
    _Pragma("unroll")                                                         \
    for (int ks = 0; ks < 2; ++ks) {                                          \
      h16x8 af[4];                                                            \
      _Pragma("unroll")                                                       \
      for (int mi = 0; mi < 4; ++mi) {                                        \
        HF8 t_;                                                               \
        f16x2 xp_; xp_[0] = xh[mi]; xp_[1] = xh[mi];                          \
        _Pragma("unroll")                                                     \
        for (int j = 0; j < 4; ++j) t_.h2[j] = prh[mi][ks].h2[j] * xp_;       \
        af[mi] = t_.v;                                                        \
      }                                                                       \
      _Pragma("unroll")                                                       \
      for (int ni = 0; ni < 4; ++ni) {                                        \
        h16x8 bfr = *(const h16x8*)(bsr_ + ni * 2048 + rbase + coff[ks]);     \
        _Pragma("unroll")                                                     \
        for (int mi = 0; mi < 4; ++mi)                                        \
          acc[mi][ni] = __builtin_amdgcn_mfma_f32_16x16x32_f16(               \
              af[mi], bfr, acc[mi][ni], 0, 0, 0);                             \
      }                                                                       \
    }                                                                         \
    __builtin_amdgcn_s_setprio(0);                                            \
    if ((IT) + 1 < KI) { BSTAGE(SNX, (BUF) ^ 1) }                             \
    if ((IT) + 5 < KI) { BLOAD((IT) + 5, SNX) }                               \
    BARRIER();                                                                \
  }

  // ---- prologue: tiles 0..3 in flight, tile0 staged, tile4 issued ----
  BLOAD(0, 0)
  BLOAD(1, 1)
  BLOAD(2, 2)
  BLOAD(3, 3)
  BSTAGE(0, 0)       // waits only for tile0 (3 newer tiles stay in flight)
  BLOAD(4, 0)
  BARRIER();         // xs + bs[0] visible

  for (int itb = 0; itb < KI; itb += 4) {
    STEP(itb + 0, 0, 1)
    STEP(itb + 1, 1, 2)
    STEP(itb + 2, 0, 3)
    STEP(itb + 3, 1, 0)
  }
#undef BLOAD
#undef BSTAGE
#undef BARRIER
#undef STEP

  // ---- epilogue ----
#pragma unroll
  for (int mi = 0; mi < 4; ++mi) {
#pragma unroll
    for (int ni = 0; ni < 4; ++ni) {
      int row = row_m0 + wm + mi * 16 + quad * 4;
      int col = o0 + ni * 16 + l15;
      if (ATOMIC) {
        float* o = dst + (size_t)row * OUT_F + col;
        atomicAdd(o,             acc[mi][ni][0]);
        atomicAdd(o + OUT_F,     acc[mi][ni][1]);
        atomicAdd(o + 2 * OUT_F, acc[mi][ni][2]);
        atomicAdd(o + 3 * OUT_F, acc[mi][ni][3]);
      } else {
        float* o = dst + ((size_t)kc << 19) + (size_t)row * OUT_F + col;
        o[0]         = acc[mi][ni][0];
        o[OUT_F]     = acc[mi][ni][1];
        o[2 * OUT_F] = acc[mi][ni][2];
        o[3 * OUT_F] = acc[mi][ni][3];
      }
    }
  }
}

// ---------------------------------------------------------------------------
// Kernel 3: out[b][o] = sum_kc parts[kc][b][o] + sum_l p[b][l]*pb[o][l]
// (unchanged; nparts==0 -> bias-only init for atomic fallback)
// ---------------------------------------------------------------------------
__global__ __launch_bounds__(256, 4) void k_reduce(
    const float* __restrict__ parts, const float* __restrict__ p_ws,
    const float* __restrict__ pb, float* __restrict__ out, int nparts)
{
  __shared__ float ps_l[2 * NLEAF];
  const int t  = threadIdx.x;
  const int b0 = blockIdx.x * 2;

  if (t < 32)
    ((f32x4*)ps_l)[t] = ((const f32x4*)(p_ws + (size_t)b0 * NLEAF))[t];
  __syncthreads();

  const int row = b0 + (t >> 7);
  const int c0  = (t & 127) * 4;
  const f32x4* ps = (const f32x4*)&ps_l[(t >> 7) * NLEAF];

  f32x4 a;
#pragma unroll
  for (int jo = 0; jo < 4; ++jo) {
    const f32x4* pbo = (const f32x4*)(pb + (size_t)(c0 + jo) * NLEAF);
    f32x4 s = (f32x4)(0.f);
#pragma unroll
    for (int lv = 0; lv < 16; ++lv) s += pbo[lv] * ps[lv];
    a[jo] = s.x + s.y + s.z + s.w;
  }

#pragma unroll 8
  for (int k = 0; k < nparts; ++k)
    a += *(const f32x4*)(parts + ((size_t)k << 19) + (size_t)row * OUT_F + c0);

  *(f32x4*)(out + (size_t)row * OUT_F + c0) = a;
}

// ---------------------------------------------------------------------------
extern "C" void kernel_launch(void* const* d_in, const int* in_sizes, int n_in,
                              void* d_out, int out_size, void* d_ws, size_t ws_size,
                              hipStream_t stream) {
  const float* xg = (const float*)d_in[0];   // x_gating [1024][512]
  const float* xl = (const float*)d_in[1];   // x_leaf   [1024][512]
  const float* gw = (const float*)d_in[2];   // [512][63]
  const float* gb = (const float*)d_in[3];   // [63]
  const float* pw = (const float*)d_in[4];   // [512][512][64]
  const float* pb = (const float*)d_in[5];   // [512][64]
  float* out = (float*)d_out;

  // ws: p fp32 (256 KB) | parts fp32 [SK][1024][512] (32 MB)
  const size_t P_BYTES = (size_t)B_SZ * NLEAF * 4;
  const size_t SLICE   = (size_t)B_SZ * OUT_F * 4;

  float* p_ws  = (float*)d_ws;
  float* parts = (float*)((char*)d_ws + P_BYTES);

  k_leafprobs<<<dim3(B_SZ), dim3(512), 0, stream>>>(xg, gw, gb, p_ws);

  if (ws_size >= P_BYTES + SK * SLICE) {
    k_fused<false><<<dim3(512), dim3(256), 0, stream>>>(xl, p_ws, pw, parts);
    k_reduce<<<dim3(512), dim3(256), 0, stream>>>(parts, p_ws, pb, out, SK);
  } else {
    k_reduce<<<dim3(512), dim3(256), 0, stream>>>(parts, p_ws, pb, out, 0);
    k_fused<true><<<dim3(512), dim3(256), 0, stream>>>(xl, p_ws, pw, out);
  }
}

// Round 4
// 166.293 us; speedup vs baseline: 1.0290x; 1.0066x over previous
//
#include <hip/hip_runtime.h>
#include <stdint.h>

// Problem constants
#define B_SZ   1024
#define GF     512
#define GC     63
#define NLEAF  64
#define IN_F   512
#define OUT_F  512

typedef float f32x4 __attribute__((ext_vector_type(4)));
// builtin-facing half types (__fp16: what cvt_pkrtz / mfma_f16 use here)
typedef __fp16 h16x2 __attribute__((ext_vector_type(2)));
typedef __fp16 h16x8 __attribute__((ext_vector_type(8)));
// arithmetic half types (_Float16: native packed math)
typedef _Float16 f16x2 __attribute__((ext_vector_type(2)));

union HF8 { f16x2 h2[4]; h16x8 v; uint4 u; };

__device__ inline f16x2 pkrtz(float a, float b) {
  union { h16x2 r; f16x2 f; } u;
  u.r = __builtin_amdgcn_cvt_pkrtz(a, b);
  return u.f;
}

// ---------------------------------------------------------------------------
// Kernel 1: gatings = sigmoid(x_gating @ gw + gb); leaf_probs tree product.
// (unchanged — proven)
// ---------------------------------------------------------------------------
__global__ __launch_bounds__(512, 2) void k_leafprobs(
    const float* __restrict__ xg, const float* __restrict__ gw,
    const float* __restrict__ gb, float* __restrict__ p_ws)
{
  __shared__ float xsr[GF];
  __shared__ float part[512];
  __shared__ float gates[GC + 1];
  const int b = blockIdx.x;
  const int t = threadIdx.x;

  xsr[t] = xg[(size_t)b * GF + t];
  __syncthreads();

  const int ks = t >> 6, g = t & 63;
  float acc = 0.f;
  if (g < GC) {
    const float* gp = gw + (size_t)(ks * 64) * GC + g;
    const float* xp = &xsr[ks * 64];
#pragma unroll 8
    for (int k = 0; k < 64; ++k) acc += xp[k] * gp[(size_t)k * GC];
  }
  part[t] = acc;
  __syncthreads();

  if (t < GC) {
    float s = gb[t];
#pragma unroll
    for (int r = 0; r < 8; ++r) s += part[r * 64 + t];
    gates[t] = 1.f / (1.f + expf(-s));
  }
  __syncthreads();

  if (t < NLEAF) {
    float v = 1.f;
    int idx = 0, start = 0;
#pragma unroll
    for (int d = 0; d < 6; ++d) {
      int bit = (t >> (5 - d)) & 1;
      float gg = gates[start + idx];
      v *= bit ? (1.f - gg) : gg;
      idx = 2 * idx + bit;
      start += (1 << d);
    }
    p_ws[(size_t)b * NLEAF + t] = v;
  }
}

// ---------------------------------------------------------------------------
// Kernel 2 (FUSED): same structure as R3 but the B-prefetch is PINNED:
//  * BLOAD = volatile inline-asm global_load_dwordx4 (cannot sink; compiler
//    waitcnt tracking ignores it -> no hidden vmcnt(0))
//  * BWAIT = manual counted s_waitcnt vmcnt(N), rb values tied via "+v"
//    so consumers can't hoist above it; sched_barrier(0) after (rule 18)
//  * steady state keeps 3 tiles (12 loads) in flight ACROSS barriers
//  R3 evidence: VGPR_Count=108 == acc+prh+misc -> compiler gave the 4-deep
//  rb prefetch ZERO registers and sank loads to use => ~2600 cyc/phase
//  latency stall. This version forces the registers (expect VGPR ~180).
// ---------------------------------------------------------------------------
#define SK 16
#define KI 32   // 512 / SK

template <bool ATOMIC>
__global__ __launch_bounds__(256, 2) void k_fused(
    const float* __restrict__ x_leaf,   // [1024][512]
    const float* __restrict__ p_ws,     // [1024][64]
    const float* __restrict__ pw,       // [512][512][64]  ([o][i][l])
    float* __restrict__ dst)            // parts [SK][1024][512] or out
{
  __shared__ __align__(16) float         xs[KI][256];   // 32 KB (transposed)
  __shared__ __align__(16) unsigned char bs8[2 * 8192]; // 16 KB f16, swizzled

  const int tid  = threadIdx.x;
  const int lane = tid & 63;
  const int wid  = tid >> 6;        // 0..3
  const int quad = lane >> 4;
  const int l15  = lane & 15;
  const int l7   = l15 & 7;

  const int bid = blockIdx.x;       // 512
  const int nt  = bid & 7;
  const int mt  = (bid >> 3) & 3;
  const int kc  = bid >> 5;         // 0..15

  const int row_m0 = mt * 256;
  const int o0     = nt * 64;
  const int i0     = kc * KI;
  const int wm     = wid * 64;      // 64 rows per wave

  // ---- stage x slab transposed [KI][256]: one row per thread ----
  {
    const float* src = x_leaf + (size_t)(row_m0 + tid) * IN_F + i0;
#pragma unroll
    for (int q = 0; q < 8; ++q) {
      float4 v = *(const float4*)(src + q * 4);
      xs[q * 4 + 0][tid] = v.x;
      xs[q * 4 + 1][tid] = v.y;
      xs[q * 4 + 2][tid] = v.z;
      xs[q * 4 + 3][tid] = v.w;
    }
  }

  // ---- p fragments, converted ONCE to f16 (reused all K) ----
  HF8 prh[4][2];
#pragma unroll
  for (int mi = 0; mi < 4; ++mi) {
    const int row = row_m0 + wm + mi * 16 + l15;
#pragma unroll
    for (int ks = 0; ks < 2; ++ks) {
      const f32x4* src = (const f32x4*)(p_ws + (size_t)row * NLEAF + ks * 32 + quad * 8);
      f32x4 lo = src[0], hi = src[1];
      prh[mi][ks].h2[0] = pkrtz(lo[0], lo[1]);
      prh[mi][ks].h2[1] = pkrtz(lo[2], lo[3]);
      prh[mi][ks].h2[2] = pkrtz(hi[0], hi[1]);
      prh[mi][ks].h2[3] = pkrtz(hi[2], hi[3]);
    }
  }

  // ---- B-load geometry: thread = (br = tid>>2 of 64 o-rows, seg = tid&3) ----
  const int br  = tid >> 2;
  const int seg = tid & 3;
  const float* bsrc0 = pw + ((size_t)(o0 + br) * IN_F + i0) * NLEAF + seg * 16;

  // swizzled LDS offsets (XOR touches byte bits 4-6 only; fields don't carry)
  const int wsw   = (br & 7) << 4;
  const int woff0 = br * 128 + ((seg * 32) ^ wsw);
  const int woff1 = br * 128 + ((seg * 32 + 16) ^ wsw);
  int coff[2];
#pragma unroll
  for (int ks = 0; ks < 2; ++ks)
    coff[ks] = (ks * 64 + quad * 16) ^ (l7 << 4);
  const int rbase = l15 * 128;

  f32x4 acc[4][4];
#pragma unroll
  for (int mi = 0; mi < 4; ++mi)
#pragma unroll
    for (int ni = 0; ni < 4; ++ni)
      acc[mi][ni] = (f32x4)(0.f);

  f32x4 rb[4][4];   // 4-deep register prefetch — PINNED via asm loads

  // volatile asm loads: issue exactly here, never sink, not tracked by
  // the compiler's waitcnt insertion (we count vmcnt ourselves).
#define BLOAD(T, SLOT)                                                        \
  {                                                                           \
    const float* a_ = bsrc0 + (size_t)(T) * NLEAF;                            \
    asm volatile(                                                             \
        "global_load_dwordx4 %0, %4, off\n\t"                                 \
        "global_load_dwordx4 %1, %4, off offset:16\n\t"                       \
        "global_load_dwordx4 %2, %4, off offset:32\n\t"                       \
        "global_load_dwordx4 %3, %4, off offset:48"                           \
        : "=v"(rb[SLOT][0]), "=v"(rb[SLOT][1]),                               \
          "=v"(rb[SLOT][2]), "=v"(rb[SLOT][3])                                \
        : "v"(a_));                                                           \
  }

  // counted wait: N = 4 * (#tiles issued after tile in SLOT). Ties rb
  // through the asm so no consumer hoists above the wait.
#define BWAIT_(SLOT, N)                                                       \
  asm volatile("s_waitcnt vmcnt(" #N ")"                                      \
               : "+v"(rb[SLOT][0]), "+v"(rb[SLOT][1]),                        \
                 "+v"(rb[SLOT][2]), "+v"(rb[SLOT][3])::"memory");             \
  __builtin_amdgcn_sched_barrier(0);
#define BWAIT(SLOT, N) BWAIT_(SLOT, N)

#define BSTAGE(SLOT, BUF)                                                     \
  {                                                                           \
    HF8 c0_, c1_;                                                             \
    f32x4 a0_ = rb[SLOT][0], a1_ = rb[SLOT][1];                               \
    f32x4 a2_ = rb[SLOT][2], a3_ = rb[SLOT][3];                               \
    c0_.h2[0] = pkrtz(a0_[0], a0_[1]);                                        \
    c0_.h2[1] = pkrtz(a0_[2], a0_[3]);                                        \
    c0_.h2[2] = pkrtz(a1_[0], a1_[1]);                                        \
    c0_.h2[3] = pkrtz(a1_[2], a1_[3]);                                        \
    c1_.h2[0] = pkrtz(a2_[0], a2_[1]);                                        \
    c1_.h2[1] = pkrtz(a2_[2], a2_[3]);                                        \
    c1_.h2[2] = pkrtz(a3_[0], a3_[1]);                                        \
    c1_.h2[3] = pkrtz(a3_[2], a3_[3]);                                        \
    *(uint4*)(bs8 + (BUF) * 8192 + woff0) = c0_.u;                            \
    *(uint4*)(bs8 + (BUF) * 8192 + woff1) = c1_.u;                            \
  }

  // own DS ops drained, then workgroup barrier — NO vmcnt drain: the pinned
  // global B-prefetch stays in flight across barriers.
#define BARRIER() asm volatile("s_waitcnt lgkmcnt(0)\n\ts_barrier" ::: "memory")

#define COMPUTE(IT, BUF)                                                      \
  {                                                                           \
    float xvf[4];                                                             \
    _Float16 xh[4];                                                           \
    _Pragma("unroll")                                                         \
    for (int mi = 0; mi < 4; ++mi) xvf[mi] = xs[(IT)][wm + mi * 16 + l15];    \
    _Pragma("unroll")                                                         \
    for (int mi = 0; mi < 4; ++mi) xh[mi] = (_Float16)xvf[mi];                \
    const unsigned char* bsr_ = bs8 + (BUF) * 8192;                           \
    __builtin_amdgcn_s_setprio(1);                                            \
    _Pragma("unroll")                                                         \
    for (int ks = 0; ks < 2; ++ks) {                                          \
      h16x8 af[4];                                                            \
      _Pragma("unroll")                                                       \
      for (int mi = 0; mi < 4; ++mi) {                                        \
        HF8 t_;                                                               \
        f16x2 xp_; xp_[0] = xh[mi]; xp_[1] = xh[mi];                          \
        _Pragma("unroll")                                                     \
        for (int j = 0; j < 4; ++j) t_.h2[j] = prh[mi][ks].h2[j] * xp_;       \
        af[mi] = t_.v;                                                        \
      }                                                                       \
      _Pragma("unroll")                                                       \
      for (int ni = 0; ni < 4; ++ni) {                                        \
        h16x8 bfr = *(const h16x8*)(bsr_ + ni * 2048 + rbase + coff[ks]);     \
        _Pragma("unroll")                                                     \
        for (int mi = 0; mi < 4; ++mi)                                        \
          acc[mi][ni] = __builtin_amdgcn_mfma_f32_16x16x32_f16(               \
              af[mi], bfr, acc[mi][ni], 0, 0, 0);                             \
      }                                                                       \
    }                                                                         \
    __builtin_amdgcn_s_setprio(0);                                            \
  }

// one pipeline step: compute tile IT from bs[BUF]; wait (counted) for tile
// IT+1 in slot SNX; stage it into bs[BUF^1]; optionally refill slot with
// tile IT+5; barrier (lgkm only).
#define STEP(IT, BUF, SNX, WN, DL)                                            \
  {                                                                           \
    COMPUTE(IT, BUF)                                                          \
    BWAIT(SNX, WN)                                                            \
    BSTAGE(SNX, (BUF) ^ 1)                                                    \
    if (DL) { BLOAD((IT) + 5, SNX) }                                          \
    BARRIER();                                                                \
  }

  // ---- prologue: tiles 0..3 issued; wait tile0 (3 newer stay in flight) ----
  BLOAD(0, 0)
  BLOAD(1, 1)
  BLOAD(2, 2)
  BLOAD(3, 3)
  BWAIT(0, 12)
  BSTAGE(0, 0)
  BLOAD(4, 0)
  BARRIER();         // xs + bs[0] visible

  // ---- steady: STEPs 0..23, always load, always vmcnt(12) ----
  for (int itb = 0; itb < 24; itb += 4) {
    STEP(itb + 0, 0, 1, 12, 1)
    STEP(itb + 1, 1, 2, 12, 1)
    STEP(itb + 2, 0, 3, 12, 1)
    STEP(itb + 3, 1, 0, 12, 1)
  }
  // ---- tail: literal ITs, counted drain 12 -> 8 -> 4 -> 0 ----
  STEP(24, 0, 1, 12, 1)   // loads tile 29
  STEP(25, 1, 2, 12, 1)   // loads tile 30
  STEP(26, 0, 3, 12, 1)   // loads tile 31
  STEP(27, 1, 0, 12, 0)   // stage 28; 29,30,31 outstanding
  STEP(28, 0, 1, 8, 0)    // stage 29; 30,31 outstanding
  STEP(29, 1, 2, 4, 0)    // stage 30; 31 outstanding
  STEP(30, 0, 3, 0, 0)    // stage 31; drain
  COMPUTE(31, 1)          // last tile, no stage

#undef BLOAD
#undef BWAIT
#undef BWAIT_
#undef BSTAGE
#undef BARRIER
#undef COMPUTE
#undef STEP

  // ---- epilogue ----
#pragma unroll
  for (int mi = 0; mi < 4; ++mi) {
#pragma unroll
    for (int ni = 0; ni < 4; ++ni) {
      int row = row_m0 + wm + mi * 16 + quad * 4;
      int col = o0 + ni * 16 + l15;
      if (ATOMIC) {
        float* o = dst + (size_t)row * OUT_F + col;
        atomicAdd(o,             acc[mi][ni][0]);
        atomicAdd(o + OUT_F,     acc[mi][ni][1]);
        atomicAdd(o + 2 * OUT_F, acc[mi][ni][2]);
        atomicAdd(o + 3 * OUT_F, acc[mi][ni][3]);
      } else {
        float* o = dst + ((size_t)kc << 19) + (size_t)row * OUT_F + col;
        o[0]         = acc[mi][ni][0];
        o[OUT_F]     = acc[mi][ni][1];
        o[2 * OUT_F] = acc[mi][ni][2];
        o[3 * OUT_F] = acc[mi][ni][3];
      }
    }
  }
}

// ---------------------------------------------------------------------------
// Kernel 3: out[b][o] = sum_kc parts[kc][b][o] + sum_l p[b][l]*pb[o][l]
// (unchanged; nparts==0 -> bias-only init for atomic fallback)
// ---------------------------------------------------------------------------
__global__ __launch_bounds__(256, 4) void k_reduce(
    const float* __restrict__ parts, const float* __restrict__ p_ws,
    const float* __restrict__ pb, float* __restrict__ out, int nparts)
{
  __shared__ float ps_l[2 * NLEAF];
  const int t  = threadIdx.x;
  const int b0 = blockIdx.x * 2;

  if (t < 32)
    ((f32x4*)ps_l)[t] = ((const f32x4*)(p_ws + (size_t)b0 * NLEAF))[t];
  __syncthreads();

  const int row = b0 + (t >> 7);
  const int c0  = (t & 127) * 4;
  const f32x4* ps = (const f32x4*)&ps_l[(t >> 7) * NLEAF];

  f32x4 a;
#pragma unroll
  for (int jo = 0; jo < 4; ++jo) {
    const f32x4* pbo = (const f32x4*)(pb + (size_t)(c0 + jo) * NLEAF);
    f32x4 s = (f32x4)(0.f);
#pragma unroll
    for (int lv = 0; lv < 16; ++lv) s += pbo[lv] * ps[lv];
    a[jo] = s[0] + s[1] + s[2] + s[3];
  }

#pragma unroll 8
  for (int k = 0; k < nparts; ++k)
    a += *(const f32x4*)(parts + ((size_t)k << 19) + (size_t)row * OUT_F + c0);

  *(f32x4*)(out + (size_t)row * OUT_F + c0) = a;
}

// ---------------------------------------------------------------------------
extern "C" void kernel_launch(void* const* d_in, const int* in_sizes, int n_in,
                              void* d_out, int out_size, void* d_ws, size_t ws_size,
                              hipStream_t stream) {
  const float* xg = (const float*)d_in[0];   // x_gating [1024][512]
  const float* xl = (const float*)d_in[1];   // x_leaf   [1024][512]
  const float* gw = (const float*)d_in[2];   // [512][63]
  const float* gb = (const float*)d_in[3];   // [63]
  const float* pw = (const float*)d_in[4];   // [512][512][64]
  const float* pb = (const float*)d_in[5];   // [512][64]
  float* out = (float*)d_out;

  // ws: p fp32 (256 KB) | parts fp32 [SK][1024][512] (32 MB)
  const size_t P_BYTES = (size_t)B_SZ * NLEAF * 4;
  const size_t SLICE   = (size_t)B_SZ * OUT_F * 4;

  float* p_ws  = (float*)d_ws;
  float* parts = (float*)((char*)d_ws + P_BYTES);

  k_leafprobs<<<dim3(B_SZ), dim3(512), 0, stream>>>(xg, gw, gb, p_ws);

  if (ws_size >= P_BYTES + SK * SLICE) {
    k_fused<false><<<dim3(512), dim3(256), 0, stream>>>(xl, p_ws, pw, parts);
    k_reduce<<<dim3(512), dim3(256), 0, stream>>>(parts, p_ws, pb, out, SK);
  } else {
    k_reduce<<<dim3(512), dim3(256), 0, stream>>>(parts, p_ws, pb, out, 0);
    k_fused<true><<<dim3(512), dim3(256), 0, stream>>>(xl, p_ws, pw, out);
  }
}